// Round 14
// baseline (4097.050 us; speedup 1.0000x reference)
//
#include <hip/hip_runtime.h>
#include <hip/hip_fp16.h>

#define HDIM 256
#define LSEQ 512
#define PRED 96
#define NTHR 1024

__device__ __forceinline__ float sigm(float x) { return 1.f / (1.f + __expf(-x)); }
__device__ __forceinline__ float tanh_(float x) { float t = __expf(2.f * x); return 1.f - 2.f / (t + 1.f); }

// quad butterfly (lanes xor 1, xor 2) via DPP quad_perm — pure VALU, no LDS pipe.
__device__ __forceinline__ float qred(float v) {
  v += __builtin_bit_cast(float, __builtin_amdgcn_update_dpp(
           0, __builtin_bit_cast(int, v), 0xB1, 0xF, 0xF, true));  // quad_perm [1,0,3,2]
  v += __builtin_bit_cast(float, __builtin_amdgcn_update_dpp(
           0, __builtin_bit_cast(int, v), 0x4E, 0xF, 0xF, true));  // quad_perm [2,3,0,1]
  return v;
}

struct SmemT {
  // packed-f16 h state, compensated: h = hi + lo (lo = f16 of the hi-residual).
  // [buf][quad][32 pairs + 4 pad]: quad stride 36 dwords -> chunk c of quad q
  // lands on banks 4q+4c (16 distinct banks per b128 sweep) — conflict-free.
  unsigned int hhi[2][4][36];
  unsigned int hlo[2][4][36];
  float hf[2][258];   // exact f32 h for the z*hold term (non-compounding state)
  float xv[LSEQ];
  float wih[768];     // rank-1 input weights for scalar-input phases
  float bih[768];
  float bhh[768];
  float wo[HDIM];
  float red[16];
  float inp;
};

// pack 2 fp32 -> 1 u32 of 2 f16 (RN) — arch-resident weight pair
#define WPK(D, X, Y)                                                               \
  { __half2 _h = __floats2half2_rn((X), (Y));                                      \
    (D) = __builtin_bit_cast(unsigned int, _h); }

// AGPR write (R7-proven): claims the acc half of the unified RF
#define AW(A, X, Y)                                                                \
  { __half2 _h = __floats2half2_rn((X), (Y));                                      \
    unsigned int _u = __builtin_bit_cast(unsigned int, _h);                        \
    asm("v_accvgpr_write_b32 %0, %1" : "=a"(A) : "v"(_u)); }
#define AWP(A, F2) AW(A, (F2).x, (F2).y)

// This thread's 3 gate rows (64-wide k-slice) of [768][256] fp32:
// r -> 32 arch u32 pairs; z,n -> 64 AGPR pairs.
#define LOADW(PTR)                                                                 \
  {                                                                                \
    const float4* r4 = (const float4*)((PTR) + (size_t)j * HDIM + k0);             \
    float4 f;                                                                      \
    f=r4[0];  WPK(wp00,f.x,f.y) WPK(wp01,f.z,f.w)                                  \
    f=r4[1];  WPK(wp02,f.x,f.y) WPK(wp03,f.z,f.w)                                  \
    f=r4[2];  WPK(wp04,f.x,f.y) WPK(wp05,f.z,f.w)                                  \
    f=r4[3];  WPK(wp06,f.x,f.y) WPK(wp07,f.z,f.w)                                  \
    f=r4[4];  WPK(wp08,f.x,f.y) WPK(wp09,f.z,f.w)                                  \
    f=r4[5];  WPK(wp10,f.x,f.y) WPK(wp11,f.z,f.w)                                  \
    f=r4[6];  WPK(wp12,f.x,f.y) WPK(wp13,f.z,f.w)                                  \
    f=r4[7];  WPK(wp14,f.x,f.y) WPK(wp15,f.z,f.w)                                  \
    f=r4[8];  WPK(wp16,f.x,f.y) WPK(wp17,f.z,f.w)                                  \
    f=r4[9];  WPK(wp18,f.x,f.y) WPK(wp19,f.z,f.w)                                  \
    f=r4[10]; WPK(wp20,f.x,f.y) WPK(wp21,f.z,f.w)                                  \
    f=r4[11]; WPK(wp22,f.x,f.y) WPK(wp23,f.z,f.w)                                  \
    f=r4[12]; WPK(wp24,f.x,f.y) WPK(wp25,f.z,f.w)                                  \
    f=r4[13]; WPK(wp26,f.x,f.y) WPK(wp27,f.z,f.w)                                  \
    f=r4[14]; WPK(wp28,f.x,f.y) WPK(wp29,f.z,f.w)                                  \
    f=r4[15]; WPK(wp30,f.x,f.y) WPK(wp31,f.z,f.w)                                  \
    const float2* z2 = (const float2*)((PTR) + (size_t)(j + 256) * HDIM + k0);     \
    const float2* n2 = (const float2*)((PTR) + (size_t)(j + 512) * HDIM + k0);     \
    AWP(az00,z2[0])  AWP(az01,z2[1])  AWP(az02,z2[2])  AWP(az03,z2[3])             \
    AWP(az04,z2[4])  AWP(az05,z2[5])  AWP(az06,z2[6])  AWP(az07,z2[7])             \
    AWP(az08,z2[8])  AWP(az09,z2[9])  AWP(az10,z2[10]) AWP(az11,z2[11])            \
    AWP(az12,z2[12]) AWP(az13,z2[13]) AWP(az14,z2[14]) AWP(az15,z2[15])            \
    AWP(az16,z2[16]) AWP(az17,z2[17]) AWP(az18,z2[18]) AWP(az19,z2[19])            \
    AWP(az20,z2[20]) AWP(az21,z2[21]) AWP(az22,z2[22]) AWP(az23,z2[23])            \
    AWP(az24,z2[24]) AWP(az25,z2[25]) AWP(az26,z2[26]) AWP(az27,z2[27])            \
    AWP(az28,z2[28]) AWP(az29,z2[29]) AWP(az30,z2[30]) AWP(az31,z2[31])            \
    AWP(an00,n2[0])  AWP(an01,n2[1])  AWP(an02,n2[2])  AWP(an03,n2[3])             \
    AWP(an04,n2[4])  AWP(an05,n2[5])  AWP(an06,n2[6])  AWP(an07,n2[7])             \
    AWP(an08,n2[8])  AWP(an09,n2[9])  AWP(an10,n2[10]) AWP(an11,n2[11])            \
    AWP(an12,n2[12]) AWP(an13,n2[13]) AWP(an14,n2[14]) AWP(an15,n2[15])            \
    AWP(an16,n2[16]) AWP(an17,n2[17]) AWP(an18,n2[18]) AWP(an19,n2[19])            \
    AWP(an20,n2[20]) AWP(an21,n2[21]) AWP(an22,n2[22]) AWP(an23,n2[23])            \
    AWP(an24,n2[24]) AWP(an25,n2[25]) AWP(an26,n2[26]) AWP(an27,n2[27])            \
    AWP(an28,n2[28]) AWP(an29,n2[29]) AWP(an30,n2[30]) AWP(an31,n2[31])            \
  }

// 4 MACs in 2 inst: acc += w.(hi pair) + w.(lo pair). f16 products exact in f32,
// so hi+lo reconstructs the f32 h to 2^-22 — weight-quant remains the only error.
#define DOT2V2(ACC, W, HP, LP)                                                     \
  asm("v_dot2_f32_f16 %0, %1, %2, %0\n\t"                                          \
      "v_dot2_f32_f16 %0, %1, %3, %0"                                              \
      : "+v"(ACC) : "v"(W), "v"(HP), "v"(LP));

// AGPR-weight variant: 1 read + 2 dot2 = 4 MACs in 3 inst
#define DOT2A2(ACC, A_, HP, LP)                                                    \
  { unsigned int _t;                                                               \
    asm("v_accvgpr_read_b32 %1, %2\n\t"                                            \
        "v_dot2_f32_f16 %0, %1, %3, %0\n\t"                                        \
        "v_dot2_f32_f16 %0, %1, %4, %0"                                            \
        : "+v"(ACC), "=&v"(_t) : "a"(A_), "v"(HP), "v"(LP)); }

// one hi/lo uint4 pair (8 k) -> 24 MACs across 3 gates
#define MCC(C, WA, WB, WC, WD, ZA, ZB, ZC, ZD, NA, NB, NC, ND)                     \
  { const uint4 _h = hq[C]; const uint4 _l = lq[C];                                \
    DOT2V2(ar, WA, _h.x, _l.x) DOT2V2(ar, WB, _h.y, _l.y)                          \
    DOT2V2(ar, WC, _h.z, _l.z) DOT2V2(ar, WD, _h.w, _l.w)                          \
    DOT2A2(az, ZA, _h.x, _l.x) DOT2A2(az, ZB, _h.y, _l.y)                          \
    DOT2A2(az, ZC, _h.z, _l.z) DOT2A2(az, ZD, _h.w, _l.w)                          \
    DOT2A2(an, NA, _h.x, _l.x) DOT2A2(an, NB, _h.y, _l.y)                          \
    DOT2A2(an, NC, _h.z, _l.z) DOT2A2(an, ND, _h.w, _l.w) }

// 3-gate compensated dot over this thread's 64-wide k-slice + quad butterfly.
#define MATVEC(PB)                                                                 \
  { ar = 0.f; az = 0.f; an = 0.f;                                                  \
    const uint4* hq = (const uint4*)&s.hhi[PB][q][0];                              \
    const uint4* lq = (const uint4*)&s.hlo[PB][q][0];                              \
    MCC(0, wp00,wp01,wp02,wp03, az00,az01,az02,az03, an00,an01,an02,an03)          \
    MCC(1, wp04,wp05,wp06,wp07, az04,az05,az06,az07, an04,an05,an06,an07)          \
    MCC(2, wp08,wp09,wp10,wp11, az08,az09,az10,az11, an08,an09,an10,an11)          \
    MCC(3, wp12,wp13,wp14,wp15, az12,az13,az14,az15, an12,an13,an14,an15)          \
    MCC(4, wp16,wp17,wp18,wp19, az16,az17,az18,az19, an16,an17,an18,an19)          \
    MCC(5, wp20,wp21,wp22,wp23, az20,az21,az22,az23, an20,an21,an22,an23)          \
    MCC(6, wp24,wp25,wp26,wp27, az24,az25,az26,az27, an24,an25,an26,an27)          \
    MCC(7, wp28,wp29,wp30,wp31, az28,az29,az30,az31, an28,an29,an30,an31)          \
    ar = qred(ar); az = qred(az); an = qred(an); }

// state writer (q==0): hi/lo packed f16 + exact f32
#define HWRITE(PB1, HN)                                                            \
  { const __half _hi = __float2half(HN);                                           \
    const __half _lo = __float2half((HN) - __half2float(_hi));                     \
    ((__half*)s.hhi[PB1][j >> 6])[j & 63] = _hi;                                   \
    ((__half*)s.hlo[PB1][j >> 6])[j & 63] = _lo;                                   \
    s.hf[PB1][j] = (HN); }

#define DECL_WREGS                                                                 \
  unsigned int wp00,wp01,wp02,wp03,wp04,wp05,wp06,wp07,wp08,wp09,wp10,wp11,wp12,   \
      wp13,wp14,wp15,wp16,wp17,wp18,wp19,wp20,wp21,wp22,wp23,wp24,wp25,wp26,wp27,  \
      wp28,wp29,wp30,wp31;                                                         \
  unsigned int                                                                     \
      az00,az01,az02,az03,az04,az05,az06,az07,az08,az09,az10,az11,az12,az13,az14,az15, \
      az16,az17,az18,az19,az20,az21,az22,az23,az24,az25,az26,az27,az28,az29,az30,az31, \
      an00,an01,an02,an03,an04,an05,an06,an07,an08,an09,an10,an11,an12,an13,an14,an15, \
      an16,an17,an18,an19,an20,an21,an22,an23,an24,an25,an26,an27,an28,an29,an30,an31; \
  float ar, az, an;

// =================== Kernel 1: encoder GRU layer 0 (sequential) ===============
__global__ __attribute__((amdgpu_flat_work_group_size(NTHR, NTHR), amdgpu_waves_per_eu(4, 4)))
void gru_p1(const float* __restrict__ x,
            const float* __restrict__ Wih0, const float* __restrict__ Whh0,
            const float* __restrict__ bih0, const float* __restrict__ bhh0,
            __half* __restrict__ ys) {
  __shared__ SmemT s;
  const int tid = threadIdx.x;
  const int b = blockIdx.x;
  const int j = tid >> 2;
  const int q = tid & 3;
  const int k0 = q << 6;
  DECL_WREGS

  if (tid < LSEQ) s.xv[tid] = x[(size_t)b * LSEQ + tid];
  if (tid < 768) { s.wih[tid] = Wih0[tid]; s.bih[tid] = bih0[tid]; s.bhh[tid] = bhh0[tid]; }
  if (tid < 144) { ((unsigned int*)s.hhi[0])[tid] = 0u; ((unsigned int*)s.hlo[0])[tid] = 0u; }
  if (tid < 256) s.hf[0][tid] = 0.f;
  LOADW(Whh0);
  __syncthreads();

  int pb = 0;
  for (int t = 0; t < LSEQ; ++t) {
    MATVEC(pb);
    const float xt = s.xv[t];
    const float ghr = ar + s.bhh[j], ghz = az + s.bhh[j + 256], ghn = an + s.bhh[j + 512];
    const float r = sigm(fmaf(xt, s.wih[j], s.bih[j]) + ghr);
    const float z = sigm(fmaf(xt, s.wih[j + 256], s.bih[j + 256]) + ghz);
    const float n = tanh_(fmaf(r, ghn, fmaf(xt, s.wih[j + 512], s.bih[j + 512])));
    const float hold = s.hf[pb][j];
    const float hn = fmaf(z, hold - n, n);
    if (q == 0) {
      HWRITE(pb ^ 1, hn);
      ys[((size_t)b * LSEQ + t) * HDIM + j] = __float2half(hn);  // == hi; |h| < 1
    }
    pb ^= 1;
    __syncthreads();
  }
}

// ============ Kernel 2: GI1 = ys0 @ W_ih1^T + b_ih1 as an MFMA GEMM ===========
// (R13-proven.) M=768, N=131072 (b,t), K=256. Layouts (m89/m91-verified):
//   A[m=lane&15][k=quad*8+i]  B[k=quad*8+i][n=lane&15]  D[m=quad*4+reg][n=lane&15]
typedef _Float16 f16x8 __attribute__((ext_vector_type(8)));
typedef float f32x4 __attribute__((ext_vector_type(4)));

__global__ __launch_bounds__(256) void gemm_gi(
    const float* __restrict__ Wih1, const float* __restrict__ bih1,
    const __half* __restrict__ ys, __half* __restrict__ gi) {
  const int lane = threadIdx.x & 63;
  const int wv = threadIdx.x >> 6;            // 0..3
  const size_t bt0 = (size_t)blockIdx.x << 4; // 16 (b,t) columns
  const int n = lane & 15, q = lane >> 4;

  f16x8 bfr[8];
  const __half* yrow = ys + (bt0 + n) * HDIM + q * 8;
#pragma unroll
  for (int kk = 0; kk < 8; ++kk) bfr[kk] = *(const f16x8*)(yrow + kk * 32);

#pragma unroll 1
  for (int mt = 0; mt < 12; ++mt) {
    const int j0 = (wv * 12 + mt) << 4;
    const float* arow = Wih1 + (size_t)(j0 + n) * HDIM + q * 8;
    f32x4 acc = {0.f, 0.f, 0.f, 0.f};
#pragma unroll
    for (int kk = 0; kk < 8; ++kk) {
      const float4 a0 = *(const float4*)(arow + kk * 32);
      const float4 a1 = *(const float4*)(arow + kk * 32 + 4);
      f16x8 af;
      af[0] = (_Float16)a0.x; af[1] = (_Float16)a0.y;
      af[2] = (_Float16)a0.z; af[3] = (_Float16)a0.w;
      af[4] = (_Float16)a1.x; af[5] = (_Float16)a1.y;
      af[6] = (_Float16)a1.z; af[7] = (_Float16)a1.w;
      acc = __builtin_amdgcn_mfma_f32_16x16x32_f16(af, bfr[kk], acc, 0, 0, 0);
    }
    const int jr = j0 + (q << 2);
    __half o4[4];
#pragma unroll
    for (int r2 = 0; r2 < 4; ++r2) o4[r2] = __float2half(acc[r2] + bih1[jr + r2]);
    *(uint2*)(gi + (bt0 + n) * 768 + jr) = *(uint2*)o4;
  }
}

// ====== Kernel 3: encoder GRU layer 1 (uses gi) + autoregressive decoder ======
__global__ __attribute__((amdgpu_flat_work_group_size(NTHR, NTHR), amdgpu_waves_per_eu(4, 4)))
void gru_p34(const float* __restrict__ Whh1, const float* __restrict__ bhh1,
             const float* __restrict__ Wdih, const float* __restrict__ Wdhh,
             const float* __restrict__ bdih, const float* __restrict__ bdhh,
             const float* __restrict__ Wo, const float* __restrict__ bo,
             const __half* __restrict__ gi, float* __restrict__ out) {
  __shared__ SmemT s;
  const int tid = threadIdx.x;
  const int b = blockIdx.x;
  const int j = tid >> 2;
  const int q = tid & 3;
  const int k0 = q << 6;
  DECL_WREGS

  // ---------------- Phase 3: encoder GRU layer 1 ----------------
  LOADW(Whh1);
  if (tid < 768) s.bhh[tid] = bhh1[tid];
  if (tid < 144) { ((unsigned int*)s.hhi[0])[tid] = 0u; ((unsigned int*)s.hlo[0])[tid] = 0u; }
  if (tid < 256) s.hf[0][tid] = 0.f;
  __syncthreads();
  int pb = 0;
  for (int t = 0; t < LSEQ; ++t) {
    const size_t o = ((size_t)b * LSEQ + t) * 768;
    const float gr = __half2float(gi[o + j]);           // prefetch; latency hidden
    const float gz = __half2float(gi[o + j + 256]);
    const float gn = __half2float(gi[o + j + 512]);
    MATVEC(pb);
    const float ghr = ar + s.bhh[j], ghz = az + s.bhh[j + 256], ghn = an + s.bhh[j + 512];
    const float r = sigm(gr + ghr);
    const float z = sigm(gz + ghz);
    const float n = tanh_(fmaf(r, ghn, gn));
    const float hold = s.hf[pb][j];
    const float hn = fmaf(z, hold - n, n);
    if (q == 0) HWRITE(pb ^ 1, hn);
    pb ^= 1;
    __syncthreads();
  }

  // ---------------- Phase 4: autoregressive decoder (96 steps) ----------------
  LOADW(Wdhh);
  if (tid < 768) { s.wih[tid] = Wdih[tid]; s.bih[tid] = bdih[tid]; s.bhh[tid] = bdhh[tid]; }
  if (tid < HDIM) s.wo[tid] = Wo[tid];
  if (tid == 0) s.inp = 0.f;
  const float bov = bo[0];
  __syncthreads();
  for (int t = 0; t < PRED; ++t) {
    const float it = s.inp;
    MATVEC(pb);
    const float ghr = ar + s.bhh[j], ghz = az + s.bhh[j + 256], ghn = an + s.bhh[j + 512];
    const float r = sigm(fmaf(it, s.wih[j], s.bih[j]) + ghr);
    const float z = sigm(fmaf(it, s.wih[j + 256], s.bih[j + 256]) + ghz);
    const float n = tanh_(fmaf(r, ghn, fmaf(it, s.wih[j + 512], s.bih[j + 512])));
    const float hold = s.hf[pb][j];
    const float hn = fmaf(z, hold - n, n);
    float c = (q == 0) ? s.wo[j] * hn : 0.f;
#pragma unroll
    for (int off = 1; off < 64; off <<= 1) c += __shfl_xor(c, off);
    if (q == 0) HWRITE(pb ^ 1, hn);
    if ((tid & 63) == 0) s.red[tid >> 6] = c;
    pb ^= 1;
    __syncthreads();
    if (tid == 0) {
      float ov = bov;
#pragma unroll
      for (int i2 = 0; i2 < 16; ++i2) ov += s.red[i2];
      out[(size_t)b * PRED + t] = ov;
      s.inp = ov;
    }
    __syncthreads();
  }
}

extern "C" void kernel_launch(void* const* d_in, const int* in_sizes, int n_in,
                              void* d_out, int out_size, void* d_ws, size_t ws_size,
                              hipStream_t stream) {
  const float* x    = (const float*)d_in[0];
  const float* Wih0 = (const float*)d_in[1];
  const float* Whh0 = (const float*)d_in[2];
  const float* bih0 = (const float*)d_in[3];
  const float* bhh0 = (const float*)d_in[4];
  const float* Wih1 = (const float*)d_in[5];
  const float* Whh1 = (const float*)d_in[6];
  const float* bih1 = (const float*)d_in[7];
  const float* bhh1 = (const float*)d_in[8];
  const float* Wdih = (const float*)d_in[9];
  const float* Wdhh = (const float*)d_in[10];
  const float* bdih = (const float*)d_in[11];
  const float* bdhh = (const float*)d_in[12];
  const float* Wo   = (const float*)d_in[13];
  const float* bo   = (const float*)d_in[14];

  // ws layout: ys0 (f16, 64 MiB) | GI1 (f16, 192 MiB)
  __half* ys = (__half*)d_ws;
  __half* gi = ys + (size_t)256 * 512 * 256;

  gru_p1<<<256, NTHR, 0, stream>>>(x, Wih0, Whh0, bih0, bhh0, ys);
  gemm_gi<<<(256 * 512) / 16, 256, 0, stream>>>(Wih1, bih1, ys, gi);
  gru_p34<<<256, NTHR, 0, stream>>>(Whh1, bhh1, Wdih, Wdhh, bdih, bdhh, Wo, bo,
                                    gi, (float*)d_out);
}